// Round 4
// baseline (26865.680 us; speedup 1.0000x reference)
//
#include <hip/hip_runtime.h>

#define SQ 1800
#define NBLK 256

typedef _Float16 h2v __attribute__((ext_vector_type(2)));
#define AGT __HIP_MEMORY_SCOPE_AGENT

__device__ __forceinline__ float bf2f(unsigned short u){ return __uint_as_float(((unsigned)u)<<16); }
__device__ __forceinline__ unsigned short f2bf(float f){
  unsigned u=__float_as_uint(f);
  unsigned r=u+0x7FFFu+((u>>16)&1u);
  return (unsigned short)(r>>16);
}
__device__ __forceinline__ float sigm(float x){ return 1.0f/(1.0f+__expf(-x)); }
__device__ __forceinline__ unsigned pack16(float a, float b){
  _Float16 ha=(_Float16)a, hb=(_Float16)b;
  unsigned short ua=__builtin_bit_cast(unsigned short,ha), ub=__builtin_bit_cast(unsigned short,hb);
  return (unsigned)ua | ((unsigned)ub<<16);
}
__device__ __forceinline__ float lo16(unsigned v){ h2v h=__builtin_bit_cast(h2v,v); return (float)h[0]; }
__device__ __forceinline__ float hi16(unsigned v){ h2v h=__builtin_bit_cast(h2v,v); return (float)h[1]; }
__device__ __forceinline__ float hdot2(unsigned uw, unsigned ux, float acc){
  h2v a=__builtin_bit_cast(h2v,uw), b=__builtin_bit_cast(h2v,ux);
#if __has_builtin(__builtin_amdgcn_fdot2)
  return __builtin_amdgcn_fdot2(a,b,acc,false);
#else
  return acc + (float)a[0]*(float)b[0] + (float)a[1]*(float)b[1];
#endif
}
__device__ __forceinline__ unsigned aload(const unsigned* p){
  return __hip_atomic_load(p,__ATOMIC_RELAXED,AGT);
}
__device__ __forceinline__ unsigned long long aload64(const unsigned long long* p){
  return __hip_atomic_load(p,__ATOMIC_RELAXED,AGT);
}
__device__ __forceinline__ void astore(unsigned* p, unsigned v){
  __hip_atomic_store(p,v,__ATOMIC_RELAXED,AGT);
}

// ---------------- prep kernels ----------------

__global__ __launch_bounds__(256) void k_postab(float* __restrict__ pt){
  int idx=blockIdx.x*256+threadIdx.x; if(idx>=SQ*200) return;
  int t=idx/200, j=idx%200;
  double ang=(double)(t+1)*pow(10000.0, -(double)(2*(j/2))/200.0);
  pt[idx]=(float)((j&1)? cos(ang) : sin(ang));
}

// W_e[k][j] = sum_m tgt_W[k][m] * Wih1[m][j]   (72 x 4096)
__global__ __launch_bounds__(256) void k_we(const float* __restrict__ tgtW, const float* __restrict__ Wih1, float* __restrict__ We){
  int idx=blockIdx.x*256+threadIdx.x;
  int k=idx>>12, j=idx&4095;
  float acc=0.f;
  for(int m=0;m<200;m++) acc+=tgtW[k*200+m]*Wih1[(size_t)m*4096+j];
  We[idx]=acc;
}

// bias[3][4096]
__global__ __launch_bounds__(256) void k_bias(const float* __restrict__ tgtb, const float* __restrict__ Wih1,
    const float* __restrict__ bih1,const float* __restrict__ bhh1,const float* __restrict__ bih2,const float* __restrict__ bhh2,
    const float* __restrict__ bih3,const float* __restrict__ bhh3,float* __restrict__ bias){
  int idx=blockIdx.x*256+threadIdx.x; if(idx>=3*4096) return;
  int l=idx>>12, j=idx&4095;
  float v;
  if(l==0){ v=bih1[j]+bhh1[j]; for(int m=0;m<200;m++) v+=tgtb[m]*Wih1[(size_t)m*4096+j]; }
  else if(l==1) v=bih2[j]+bhh2[j];
  else v=bih3[j]+bhh3[j];
  bias[idx]=v;
}

// packed f16 weights, unit-major [cell][u][k2][4gates], zero-padded k2 strides:
// cell0: 576 k2 (K=1096), stride 2304 u32 ; cell1: 1080 k2 (K=2048), stride 4320 ;
// cell2: 1088 k2 (K=2048), stride 4352.  total u32 = 11239424
__global__ __launch_bounds__(256) void k_packf(const float* __restrict__ We, const float* __restrict__ Whh1,
  const float* __restrict__ Wih2, const float* __restrict__ Whh2,
  const float* __restrict__ Wih3, const float* __restrict__ Whh3, unsigned* __restrict__ P){
  size_t idx=(size_t)blockIdx.x*256+threadIdx.x; // exactly 11,239,424
  const float *A, *Bm; size_t l; int stride, KA, K;
  if(idx < 2359296u){ l=idx; stride=2304; A=We; Bm=Whh1; KA=72; K=1096; }
  else if(idx < 6782976u){ l=idx-2359296u; stride=4320; A=Wih2; Bm=Whh2; KA=1024; K=2048; }
  else { l=idx-6782976u; stride=4352; A=Wih3; Bm=Whh3; KA=1024; K=2048; }
  int u=(int)(l/(size_t)stride); int r=(int)(l-(size_t)u*stride);
  int k2=r>>2, g=r&3, k=2*k2;
  float w0=0.f,w1=0.f;
  if(k<K){
    int col=g*1024+u;
    w0 = (k   < KA)? A[(size_t)k*4096+col]      : Bm[(size_t)(k-KA)*4096+col];
    w1 = (k+1 < KA)? A[(size_t)(k+1)*4096+col]  : Bm[(size_t)(k+1-KA)*4096+col];
  }
  P[idx]=pack16(w0,w1);
}

// outWT[j][u] = out_W[u][j] for u<1024 (h2 part), [72][1024]
__global__ __launch_bounds__(256) void k_outwt(const float* __restrict__ outW, float* __restrict__ outWT){
  int idx=blockIdx.x*256+threadIdx.x; if(idx>=72*1024) return;
  int j=idx>>10, u=idx&1023;
  outWT[idx]=outW[(size_t)u*72+j];
}

// ---------------- encoder ----------------

__global__ __launch_bounds__(256) void k_embed(const float* __restrict__ src, const float* __restrict__ W,
    const float* __restrict__ bias, const float* __restrict__ posb, float* __restrict__ xout){
  __shared__ float s[8][438];
  int row0=blockIdx.x*8, tid=threadIdx.x;
  for(int idx=tid; idx<8*438; idx+=256){ int r=idx/438,k=idx%438; s[r][k]=src[(size_t)(row0+r)*438+k]; }
  __syncthreads();
  int j=tid; if(j<200){
    float acc[8];
    #pragma unroll
    for(int r=0;r<8;r++){ int t=(row0+r)%SQ; acc[r]=bias[j]+posb[t*200+j]; }
    for(int k=0;k<438;k++){
      float w=W[(size_t)k*200+j];
      #pragma unroll
      for(int r=0;r<8;r++) acc[r]+=s[r][k]*w;
    }
    for(int r=0;r<8;r++) xout[(size_t)(row0+r)*200+j]=acc[r];
  }
}

template<int K,int N,int CPT,bool RELU>
__global__ __launch_bounds__(256) void k_gemm8(const float* __restrict__ A, const float* __restrict__ W,
    const float* __restrict__ bias, float* __restrict__ out){
  __shared__ float s[8][K];
  int row0=blockIdx.x*8, tid=threadIdx.x;
  for(int idx=tid; idx<8*K; idx+=256){ int r=idx/K,k=idx%K; s[r][k]=A[(size_t)(row0+r)*K+k]; }
  __syncthreads();
  int j0=tid*CPT;
  float acc[8][CPT];
  #pragma unroll
  for(int r=0;r<8;r++)
    #pragma unroll
    for(int c=0;c<CPT;c++) acc[r][c]=bias[j0+c];
  for(int k=0;k<K;k++){
    float w[CPT];
    #pragma unroll
    for(int c=0;c<CPT;c++) w[c]=W[(size_t)k*N+j0+c];
    #pragma unroll
    for(int r=0;r<8;r++){ float a=s[r][k];
      #pragma unroll
      for(int c=0;c<CPT;c++) acc[r][c]+=a*w[c];
    }
  }
  #pragma unroll
  for(int r=0;r<8;r++)
    #pragma unroll
    for(int c=0;c<CPT;c++){ float v=acc[r][c]; if(RELU) v=fmaxf(v,0.f); out[(size_t)(row0+r)*N+j0+c]=v; }
}

__global__ __launch_bounds__(256) void k_attn(const float* __restrict__ Q, const float* __restrict__ Km,
    const float* __restrict__ V, float* __restrict__ O){
  int bid=blockIdx.x;
  int it=bid%225; int h=(bid/225)&7; int b=bid/1800;
  int i0=it*8;
  int j0=i0-100; if(j0<0) j0=0;
  int j1=i0+7+101; if(j1>SQ) j1=SQ;
  int JN=j1-j0;
  __shared__ unsigned short kld[208][66];
  __shared__ unsigned short vld[208][66];
  __shared__ float q[8][64];
  __shared__ float sc[8][208];
  int tid=threadIdx.x;
  for(int idx=tid; idx<JN*64; idx+=256){
    int j=idx>>6, d=idx&63;
    size_t src=((size_t)(b*SQ+j0+j)*8+h)*64+d;
    kld[j][d]=f2bf(Km[src]);
    vld[j][d]=f2bf(V[src]);
  }
  for(int idx=tid; idx<8*64; idx+=256){ int r=idx>>6,d=idx&63; q[r][d]=Q[((size_t)(b*SQ+i0+r)*8+h)*64+d]; }
  __syncthreads();
  {
    int r=tid>>5, js=tid&31;
    int i=i0+r;
    for(int j=js;j<JN;j+=32){
      int jg=j0+j; int diff=i-jg; if(diff<0) diff=-diff;
      float s=-1e30f;
      if(diff<=100){
        s=0.f;
        for(int d=0;d<64;d++) s+=q[r][d]*bf2f(kld[j][d]);
        s*=0.125f;
      }
      sc[r][j]=s;
    }
  }
  __syncthreads();
  {
    int wv=tid>>6, lane=tid&63;
    for(int rr=wv*2; rr<wv*2+2; rr++){
      float m=-1e30f;
      for(int j=lane;j<JN;j+=64) m=fmaxf(m,sc[rr][j]);
      for(int o=32;o;o>>=1) m=fmaxf(m,__shfl_xor(m,o));
      float sum=0.f;
      for(int j=lane;j<JN;j+=64){ float e=__expf(sc[rr][j]-m); sc[rr][j]=e; sum+=e; }
      for(int o=32;o;o>>=1) sum+=__shfl_xor(sum,o);
      float inv=1.f/sum;
      for(int j=lane;j<JN;j+=64) sc[rr][j]*=inv;
    }
  }
  __syncthreads();
  {
    int d=tid&63, rb=tid>>6;
    for(int rr=rb; rr<8; rr+=4){
      float acc=0.f;
      for(int j=0;j<JN;j++) acc+=sc[rr][j]*bf2f(vld[j][d]);
      O[((size_t)(b*SQ+i0+rr)*8+h)*64+d]=acc;
    }
  }
}

template<int K>
__global__ __launch_bounds__(256) void k_matln(const float* __restrict__ A, const float* __restrict__ W,
    const float* __restrict__ bias, const float* __restrict__ g, const float* __restrict__ bt, float* __restrict__ x){
  __shared__ float s[8][K];
  __shared__ float y[8][200];
  int row0=blockIdx.x*8, tid=threadIdx.x;
  for(int idx=tid; idx<8*K; idx+=256){ int r=idx/K,k=idx%K; s[r][k]=A[(size_t)(row0+r)*K+k]; }
  __syncthreads();
  if(tid<200){
    int j=tid;
    float acc[8];
    #pragma unroll
    for(int r=0;r<8;r++) acc[r]=bias[j];
    for(int k=0;k<K;k++){
      float w=W[(size_t)k*200+j];
      #pragma unroll
      for(int r=0;r<8;r++) acc[r]+=s[r][k]*w;
    }
    #pragma unroll
    for(int r=0;r<8;r++) y[r][j]=acc[r]+x[(size_t)(row0+r)*200+j];
  }
  __syncthreads();
  int wv=tid>>6, lane=tid&63;
  for(int rr=wv*2; rr<wv*2+2; rr++){
    float sm=0.f,s2=0.f;
    for(int j=lane;j<200;j+=64){ float v=y[rr][j]; sm+=v; s2+=v*v; }
    for(int o=32;o;o>>=1){ sm+=__shfl_xor(sm,o); s2+=__shfl_xor(s2,o); }
    float mean=sm*(1.f/200.f);
    float var=s2*(1.f/200.f)-mean*mean;
    float inv=rsqrtf(var+1e-5f);
    for(int j=lane;j<200;j+=64) x[(size_t)(row0+rr)*200+j]=(y[rr][j]-mean)*inv*g[j]+bt[j];
  }
}

__global__ __launch_bounds__(320) void k_encpart(const float* __restrict__ x, const float* __restrict__ outW,
    const float* __restrict__ outb, float* __restrict__ ep){
  int t=blockIdx.x, tid=threadIdx.x;
  __shared__ float el[4][200];
  for(int idx=tid; idx<800; idx+=320){ int b=idx/200,k=idx%200; el[b][k]=x[((size_t)b*SQ+t)*200+k]; }
  __syncthreads();
  if(tid<288){
    int b=tid/72, j=tid%72;
    float acc=outb[j];
    for(int k=0;k<200;k++) acc+=el[b][k]*outW[(size_t)(1024+k)*72+j];
    ep[((size_t)b*SQ+t)*72+j]=acc;
  }
}

// ---------------- persistent decoder: 2-group layer pipeline ----------------
// Group A = blocks 0..127: cell0 (8 units) + cell1 (8 units) per block.
//   A@t needs dec_in(t) [tgt / fbbuf] + h0,h1(t-1) [A-internal].
// Group B = blocks 128..255: cell2 (8 units) + fb projection.
//   B@t needs h1(t-1) [poll A's release flag, pre-satisfied] + h2(t-1) [B-internal].
// Per-group 128-block tree barrier (8 groups x 16). h ring buffer depth 4
// (slot=t&3); A throttled by B's flag (lead <= 3). fb published via a
// monotone 72-count counter instead of a barrier. All relaxed agent atomics.
// bar u32 indices: grp g*32 (g<16) | topA 512 | topB 544 | flagA 576 | flagB 608 | fbcnt 640

__global__ __launch_bounds__(512,2) void k_dec(
  const uint4* __restrict__ P4, const float* __restrict__ bias,
  unsigned* __restrict__ hbufU, unsigned* __restrict__ fbbufU,
  unsigned* __restrict__ h2allU, unsigned* __restrict__ bar,
  const float* __restrict__ tgt, const float* __restrict__ bos,
  const float* __restrict__ h_init, const float* __restrict__ c_init,
  const float* __restrict__ encp, const float* __restrict__ outWT)
{
  __shared__ __align__(16) unsigned xs2[1116*4]; // 17856B: A:[dec36|h0 512|h1 512|pad], B:[h1 512|h2 512|pad]
  __shared__ float red[16*513];                  // 32832B partial sums
  __shared__ float gsum[256];
  __shared__ float c_lds[64];
  __shared__ float htmp[64];
  __shared__ float ldspad[8192];                 // 32KB pad -> ~84.5KB total => 1 block/CU
  int tid=threadIdx.x, blk=blockIdx.x;
  bool isA = blk<128;
  int lblk = isA? blk : blk-128;
  if(tid==0) ldspad[0]=0.f;

  // thread -> (slot, ks); wave-uniform boundaries (A: waves0-2=cell0, 3-7=cell1)
  int slot,ks,NKS,NIT,xoff,cell;
  if(isA){
    if(tid<192){ slot=tid/24; ks=tid-slot*24; NKS=24; NIT=24; xoff=0; cell=0; }
    else { int l=tid-192; slot=8+l/40; ks=l-(slot-8)*40; NKS=40; NIT=27; xoff=36; cell=1; }
  } else { slot=tid>>6; ks=tid&63; NKS=64; NIT=17; xoff=0; cell=2; }
  int unit = lblk*8 + (slot&7);
  size_t ubase4 = (cell==0)? (size_t)unit*576 :
                  (cell==1)? (589824u + (size_t)unit*1080) :
                             (1695744u + (size_t)unit*1088);

  // t-invariant weight preload into VGPRs
  uint4 w[27];
  #pragma unroll
  for(int i=0;i<27;i++){ if(i<NIT) w[i]=P4[ubase4 + (size_t)ks + (size_t)i*NKS]; }

  // per-thread stage descriptors (t-invariant); dty: 0=h row, 1=dec_in, 2=pad, 3=none
  int dty[3], dlp[3];
  #pragma unroll
  for(int q=0;q<3;q++){
    int r=tid+512*q; dty[q]=3; dlp[q]=0;
    if(isA){
      if(r<36){ dty[q]=1; dlp[q]=2*r; }
      else if(r<548){ dty[q]=0; dlp[q]=(r-36)*2; }          // h0: layer0
      else if(r<1060){ dty[q]=0; dlp[q]=(512+(r-548))*2; }  // h1: layer1
      else if(r<1116){ dty[q]=2; }
    } else {
      if(r<512){ dty[q]=0; dlp[q]=(512+r)*2; }              // h1: layer1
      else if(r<1024){ dty[q]=0; dlp[q]=(1024+(r-512))*2; } // h2: layer2
      else if(r<1088){ dty[q]=2; }
    }
  }

  // c state init (LDS-resident for all 1800 steps)
  if(isA){ if(tid<64){ int s=tid>>2,b=tid&3; int cl=(s<8)?0:1;
           c_lds[tid]=c_init[((size_t)cl*4+b)*1024 + lblk*8+(s&7)]; } }
  else   { if(tid<32){ int s=tid>>2,b=tid&3;
           c_lds[tid]=c_init[((size_t)2*4+b)*1024 + lblk*8+s]; } }
  __syncthreads();

  const unsigned long long* hb64=(const unsigned long long*)hbufU;
  unsigned gen=0;
  for(int t=0;t<SQ;t++){
    bool fb=(t>0)&&(t%11==0);

    // ---- B: fb projection (start of step t, h2(t-1) is B-internal & barrier'd) ----
    if(!isA && fb){
      if(lblk<72 && tid<256){
        int j=lblk, b=tid>>6, lane=tid&63, sl=(t-1)&3;
        float s=0.f;
        #pragma unroll
        for(int q=0;q<8;q++){
          int u2=lane+q*64;
          unsigned v=aload(&hbufU[(size_t)((sl*3+2)*512+u2)*4+b]);
          s += lo16(v)*outWT[(size_t)j*1024+2*u2] + hi16(v)*outWT[(size_t)j*1024+2*u2+1];
        }
        #pragma unroll
        for(int o=32;o;o>>=1) s+=__shfl_xor(s,o);
        if(lane==0) astore(&fbbufU[b*72+j], __float_as_uint(s + encp[((size_t)b*SQ+(t-1))*72+j]));
      }
      __syncthreads();  // drains vmcnt -> fbbuf stores acked before counter bump
      if(tid==0 && lblk<72) __hip_atomic_fetch_add(&bar[640],1u,__ATOMIC_RELAXED,AGT);
    }

    // ---- dependency polls ----
    if(isA){
      if(tid<64){
        if(t>=2){ while((int)aload(&bar[608]) < t-2) __builtin_amdgcn_s_sleep(1); }  // ring throttle
        if(fb){ unsigned tc=72u*(unsigned)(t/11);
                while(aload(&bar[640]) < tc) __builtin_amdgcn_s_sleep(1); }          // fb ready
      }
    } else if(t>0){
      if(tid<64){ while((int)aload(&bar[576]) < t) __builtin_amdgcn_s_sleep(1); }    // h1(t-1) ready
      __syncthreads();
    }

    // ---- stage x (f16 pairs) ----
    if(t==0){
      #pragma unroll
      for(int q=0;q<3;q++){
        int ty=dty[q]; if(ty==3) continue;
        uint4 vv={0u,0u,0u,0u};
        if(ty==1){
          int j=dlp[q];
          const float2 f0=*(const float2*)&bos[0*72+j];
          const float2 f1=*(const float2*)&bos[1*72+j];
          const float2 f2=*(const float2*)&bos[2*72+j];
          const float2 f3=*(const float2*)&bos[3*72+j];
          vv.x=pack16(f0.x,f0.y); vv.y=pack16(f1.x,f1.y);
          vv.z=pack16(f2.x,f2.y); vv.w=pack16(f3.x,f3.y);
        } else if(ty==0){
          int lp=dlp[q]>>10, pr=(dlp[q]&1023)>>1;
          const float2 f0=*(const float2*)&h_init[((size_t)lp*4+0)*1024+2*pr];
          const float2 f1=*(const float2*)&h_init[((size_t)lp*4+1)*1024+2*pr];
          const float2 f2=*(const float2*)&h_init[((size_t)lp*4+2)*1024+2*pr];
          const float2 f3=*(const float2*)&h_init[((size_t)lp*4+3)*1024+2*pr];
          vv.x=pack16(f0.x,f0.y); vv.y=pack16(f1.x,f1.y);
          vv.z=pack16(f2.x,f2.y); vv.w=pack16(f3.x,f3.y);
        }
        *(uint4*)&xs2[(size_t)(tid+512*q)*4]=vv;
      }
    } else {
      size_t pvoff=(size_t)(((t-1)&3)*3*512*2);
      #pragma unroll
      for(int q=0;q<3;q++){
        int ty=dty[q]; if(ty>=2) continue;
        uint4 vv;
        if(ty==0){
          unsigned long long a=aload64(hb64+pvoff+dlp[q]);
          unsigned long long c=aload64(hb64+pvoff+dlp[q]+1);
          vv.x=(unsigned)a; vv.y=(unsigned)(a>>32);
          vv.z=(unsigned)c; vv.w=(unsigned)(c>>32);
        } else {
          int j=dlp[q];
          if(fb){
            vv.x=pack16(__uint_as_float(aload(&fbbufU[0*72+j])),__uint_as_float(aload(&fbbufU[0*72+j+1])));
            vv.y=pack16(__uint_as_float(aload(&fbbufU[1*72+j])),__uint_as_float(aload(&fbbufU[1*72+j+1])));
            vv.z=pack16(__uint_as_float(aload(&fbbufU[2*72+j])),__uint_as_float(aload(&fbbufU[2*72+j+1])));
            vv.w=pack16(__uint_as_float(aload(&fbbufU[3*72+j])),__uint_as_float(aload(&fbbufU[3*72+j+1])));
          } else {
            const float2 f0=*(const float2*)&tgt[((size_t)0*SQ+t)*72+j];
            const float2 f1=*(const float2*)&tgt[((size_t)1*SQ+t)*72+j];
            const float2 f2=*(const float2*)&tgt[((size_t)2*SQ+t)*72+j];
            const float2 f3=*(const float2*)&tgt[((size_t)3*SQ+t)*72+j];
            vv.x=pack16(f0.x,f0.y); vv.y=pack16(f1.x,f1.y);
            vv.z=pack16(f2.x,f2.y); vv.w=pack16(f3.x,f3.y);
          }
        }
        *(uint4*)&xs2[(size_t)(tid+512*q)*4]=vv;
      }
    }
    __syncthreads();

    // ---- gates ----
    {
      float acc[16];
      #pragma unroll
      for(int a=0;a<16;a++) acc[a]=0.f;
      #pragma unroll
      for(int i=0;i<27;i++){
        if(i>=NIT) break;
        const uint4 xv=*(const uint4*)&xs2[(size_t)(xoff+ks+i*NKS)*4];
        const unsigned* wu=(const unsigned*)&w[i];
        const unsigned* xu=(const unsigned*)&xv;
        #pragma unroll
        for(int g=0;g<4;g++)
          #pragma unroll
          for(int b=0;b<4;b++)
            acc[g*4+b]=hdot2(wu[g],xu[b],acc[g*4+b]);
      }
      #pragma unroll
      for(int a=0;a<16;a++) red[a*513+tid]=acc[a];
    }
    __syncthreads();

    // ---- per-unit reduce + bias ----
    if(isA){
      if(tid<256){
        int s=tid>>4, a=tid&15;
        int base = (s<8)? s*24 : 192+(s-8)*40;
        int n = (s<8)? 24 : 40;
        float sum=0.f;
        for(int j2=0;j2<n;j2++) sum+=red[a*513+base+j2];
        int cl=(s<8)?0:1;
        gsum[tid]=sum+bias[(size_t)cl*4096+(size_t)(a>>2)*1024 + lblk*8+(s&7)];
      }
    } else {
      if(tid<128){
        int s=tid>>4, a=tid&15;
        float sum=0.f;
        for(int j2=0;j2<64;j2++) sum+=red[a*513+s*64+j2];
        gsum[tid]=sum+bias[(size_t)2*4096+(size_t)(a>>2)*1024 + lblk*8+s];
      }
    }
    __syncthreads();

    // ---- pointwise LSTM + h stores (wave 0 only; wave-internal LDS ordering) ----
    if(isA){
      if(tid<64){
        int s=tid>>2,b=tid&3;
        float gi=gsum[s*16+b],gf=gsum[s*16+4+b],gg=gsum[s*16+8+b],go=gsum[s*16+12+b];
        float cp=c_lds[tid];
        float cn=sigm(gf)*cp+sigm(gi)*tanhf(gg);
        float hn=sigm(go)*tanhf(cn);
        c_lds[tid]=cn; htmp[tid]=hn;
        if(!(tid&4)){
          unsigned v=pack16(htmp[tid],htmp[tid+4]);
          int layer=s>>3, sl=s&7;
          int pr=lblk*4+(sl>>1);
          astore(&hbufU[(size_t)(((t&3)*3+layer)*512+pr)*4+b], v);
        }
      }
    } else {
      if(tid<32){
        int s=tid>>2,b=tid&3;
        float gi=gsum[s*16+b],gf=gsum[s*16+4+b],gg=gsum[s*16+8+b],go=gsum[s*16+12+b];
        float cp=c_lds[tid];
        float cn=sigm(gf)*cp+sigm(gi)*tanhf(gg);
        float hn=sigm(go)*tanhf(cn);
        c_lds[tid]=cn; htmp[tid]=hn;
        if(!(tid&4)){
          unsigned v=pack16(htmp[tid],htmp[tid+4]);
          int pr=lblk*4+(s>>1);
          astore(&hbufU[(size_t)(((t&3)*3+2)*512+pr)*4+b], v);
          astore(&h2allU[((size_t)t*4+b)*512+pr], v);
        }
      }
    }

    // ---- per-group tree barrier (8 groups x 16 blocks each side) ----
    __syncthreads();
    if(tid==0){
      int g=blk>>4;  // A: 0..7, B: 8..15
      unsigned r=__hip_atomic_fetch_add(&bar[g*32],1u,__ATOMIC_RELAXED,AGT);
      if(r==gen*16u+15u){
        unsigned rt=__hip_atomic_fetch_add(&bar[isA?512:544],1u,__ATOMIC_RELAXED,AGT);
        if(rt==gen*8u+7u) __hip_atomic_store(&bar[isA?576:608],gen+1u,__ATOMIC_RELAXED,AGT);
      }
      unsigned f;
      do{ __builtin_amdgcn_s_sleep(1);
          f=aload(&bar[isA?576:608]);
      }while(f<gen+1u);
    }
    __syncthreads();
    gen++;
  }
}

// final: out[b][t][j] = h2(t) @ out_W[:1024] + enc_part[b][t][j]
__global__ __launch_bounds__(320) void k_out(const unsigned* __restrict__ h2allU, const float* __restrict__ outW,
    const float* __restrict__ enc_part, float* __restrict__ out){
  int t=blockIdx.x, tid=threadIdx.x;
  __shared__ float h2l[4][1024];
  for(int idx=tid; idx<2048; idx+=320){
    int b=idx>>9, p=idx&511;
    unsigned v=h2allU[((size_t)t*4+b)*512+p];
    h2l[b][2*p]=lo16(v); h2l[b][2*p+1]=hi16(v);
  }
  __syncthreads();
  if(tid<288){
    int b=tid/72, j=tid%72;
    float acc=enc_part[((size_t)b*SQ+t)*72+j];
    for(int u=0;u<1024;u++) acc+=h2l[b][u]*outW[(size_t)u*72+j];
    out[((size_t)b*SQ+t)*72+j]=acc;
  }
}

// ---------------- host ----------------
extern "C" void kernel_launch(void* const* d_in, const int* in_sizes, int n_in,
                              void* d_out, int out_size, void* d_ws, size_t ws_size,
                              hipStream_t stream) {
  (void)in_sizes; (void)n_in; (void)out_size; (void)ws_size;
  const float* src   =(const float*)d_in[0];
  const float* tgt   =(const float*)d_in[1];
  const float* bos   =(const float*)d_in[2];
  const float* h_init=(const float*)d_in[3];
  const float* c_init=(const float*)d_in[4];
  const float* eW    =(const float*)d_in[6];
  const float* eb    =(const float*)d_in[7];
  const float* Wq    =(const float*)d_in[8];
  const float* bq    =(const float*)d_in[9];
  const float* Wk    =(const float*)d_in[10];
  const float* bk    =(const float*)d_in[11];
  const float* Wv    =(const float*)d_in[12];
  const float* bv    =(const float*)d_in[13];
  const float* Wo    =(const float*)d_in[14];
  const float* bo    =(const float*)d_in[15];
  const float* ln1g  =(const float*)d_in[16];
  const float* ln1b  =(const float*)d_in[17];
  const float* W1    =(const float*)d_in[18];
  const float* b1    =(const float*)d_in[19];
  const float* W2    =(const float*)d_in[20];
  const float* b2    =(const float*)d_in[21];
  const float* ln2g  =(const float*)d_in[22];
  const float* ln2b  =(const float*)d_in[23];
  const float* tgtW  =(const float*)d_in[24];
  const float* tgtb  =(const float*)d_in[25];
  const float* Wih1  =(const float*)d_in[26];
  const float* Whh1  =(const float*)d_in[27];
  const float* bih1  =(const float*)d_in[28];
  const float* bhh1  =(const float*)d_in[29];
  const float* Wih2  =(const float*)d_in[30];
  const float* Whh2  =(const float*)d_in[31];
  const float* bih2  =(const float*)d_in[32];
  const float* bhh2  =(const float*)d_in[33];
  const float* Wih3  =(const float*)d_in[34];
  const float* Whh3  =(const float*)d_in[35];
  const float* bih3  =(const float*)d_in[36];
  const float* bhh3  =(const float*)d_in[37];
  const float* outW  =(const float*)d_in[38];
  const float* outb  =(const float*)d_in[39];
  float* out=(float*)d_out;

  char* wsb=(char*)d_ws; size_t off=0;
  auto alloc=[&](size_t bytes)->void*{ void* p=wsb+off; off+=(bytes+255)&~(size_t)255; return p; };
  unsigned* Pf   =(unsigned*)alloc((size_t)11239424*4);   // 44.96 MB packed f16 weights
  float* We   =(float*)alloc((size_t)72*4096*4);
  float* bias =(float*)alloc((size_t)3*4096*4);
  float* outWT=(float*)alloc((size_t)72*1024*4);
  unsigned* hbufU =(unsigned*)alloc((size_t)4*3*512*4*4); // depth-4 ring
  unsigned* fbbufU=(unsigned*)alloc((size_t)4*72*4);
  unsigned* bar   =(unsigned*)alloc(4096);
  float* encp =(float*)alloc((size_t)7200*72*4);
  float* posb =(float*)alloc((size_t)SQ*200*4);
  float* xb   =(float*)alloc((size_t)7200*200*4);
  float* qb   =(float*)alloc((size_t)7200*512*4);
  float* kb   =(float*)alloc((size_t)7200*512*4);
  float* vb   =(float*)alloc((size_t)7200*512*4);
  float* ob   =(float*)alloc((size_t)7200*512*4);
  unsigned* h2allU=(unsigned*)qb; // alias: dead after encoder; 14.74MB fits
  float* mid  =vb;                // alias for FFN intermediate
  (void)kb; (void)ob;

  // prep
  k_postab<<<(SQ*200+255)/256,256,0,stream>>>(posb);
  k_we<<<72*4096/256,256,0,stream>>>(tgtW,Wih1,We);
  k_bias<<<48,256,0,stream>>>(tgtb,Wih1,bih1,bhh1,bih2,bhh2,bih3,bhh3,bias);
  k_packf<<<43904,256,0,stream>>>(We,Whh1,Wih2,Whh2,Wih3,Whh3,Pf);
  k_outwt<<<(72*1024+255)/256,256,0,stream>>>(outW,outWT);

  // encoder
  k_embed<<<900,256,0,stream>>>(src,eW,eb,posb,xb);
  for(int l=0;l<2;l++){
    k_gemm8<200,512,2,false><<<900,256,0,stream>>>(xb,Wq+(size_t)l*200*512,bq+l*512,qb);
    k_gemm8<200,512,2,false><<<900,256,0,stream>>>(xb,Wk+(size_t)l*200*512,bk+l*512,kb);
    k_gemm8<200,512,2,false><<<900,256,0,stream>>>(xb,Wv+(size_t)l*200*512,bv+l*512,vb);
    k_attn<<<7200,256,0,stream>>>(qb,kb,vb,ob);
    k_matln<512><<<900,256,0,stream>>>(ob,Wo+(size_t)l*512*200,bo+l*200,ln1g+l*200,ln1b+l*200,xb);
    k_gemm8<200,1024,4,true><<<900,256,0,stream>>>(xb,W1+(size_t)l*200*1024,b1+l*1024,mid);
    k_matln<1024><<<900,256,0,stream>>>(mid,W2+(size_t)l*1024*200,b2+l*200,ln2g+l*200,ln2b+l*200,xb);
  }
  k_encpart<<<SQ,320,0,stream>>>(xb,outW,outb,encp);

  // persistent decoder (single dispatch, 2-group pipelined barriers)
  hipMemsetAsync(bar,0,4096,stream);
  k_dec<<<NBLK,512,0,stream>>>((const uint4*)Pf,bias,hbufU,fbbufU,h2allU,bar,
                               tgt,bos,h_init,c_init,encp,outWT);

  // output projection
  k_out<<<SQ,320,0,stream>>>(h2allU,outW,encp,out);
}

// Round 6
// 12728.844 us; speedup vs baseline: 2.1106x; 2.1106x over previous
//
#include <hip/hip_runtime.h>

#define SQ 1800
#define NBLK 256

typedef _Float16 h2v __attribute__((ext_vector_type(2)));
#define AGT __HIP_MEMORY_SCOPE_AGENT

__device__ __forceinline__ float bf2f(unsigned short u){ return __uint_as_float(((unsigned)u)<<16); }
__device__ __forceinline__ unsigned short f2bf(float f){
  unsigned u=__float_as_uint(f);
  unsigned r=u+0x7FFFu+((u>>16)&1u);
  return (unsigned short)(r>>16);
}
__device__ __forceinline__ float sigm(float x){ return 1.0f/(1.0f+__expf(-x)); }
__device__ __forceinline__ unsigned pack16(float a, float b){
  _Float16 ha=(_Float16)a, hb=(_Float16)b;
  unsigned short ua=__builtin_bit_cast(unsigned short,ha), ub=__builtin_bit_cast(unsigned short,hb);
  return (unsigned)ua | ((unsigned)ub<<16);
}
__device__ __forceinline__ float lo16(unsigned v){ h2v h=__builtin_bit_cast(h2v,v); return (float)h[0]; }
__device__ __forceinline__ float hi16(unsigned v){ h2v h=__builtin_bit_cast(h2v,v); return (float)h[1]; }
__device__ __forceinline__ float hdot2(unsigned uw, unsigned ux, float acc){
  h2v a=__builtin_bit_cast(h2v,uw), b=__builtin_bit_cast(h2v,ux);
#if __has_builtin(__builtin_amdgcn_fdot2)
  return __builtin_amdgcn_fdot2(a,b,acc,false);
#else
  return acc + (float)a[0]*(float)b[0] + (float)a[1]*(float)b[1];
#endif
}
__device__ __forceinline__ unsigned aload(const unsigned* p){
  return __hip_atomic_load(p,__ATOMIC_RELAXED,AGT);
}
__device__ __forceinline__ unsigned long long aload64(const unsigned long long* p){
  return __hip_atomic_load(p,__ATOMIC_RELAXED,AGT);
}
__device__ __forceinline__ void astore(unsigned* p, unsigned v){
  __hip_atomic_store(p,v,__ATOMIC_RELAXED,AGT);
}

// compile-time gate inner loop: static w[] indexing => registers (rule #20)
template<int NIT,int NKS>
__device__ __forceinline__ void gate_acc(const uint4* __restrict__ w, const unsigned* __restrict__ xs2,
                                         int ks, int xoff, float* __restrict__ acc){
  #pragma unroll
  for(int i=0;i<NIT;i++){
    const uint4 xv=*(const uint4*)&xs2[(size_t)(xoff+ks+i*NKS)*4];
    const unsigned* wu=(const unsigned*)&w[i];
    const unsigned* xu=(const unsigned*)&xv;
    #pragma unroll
    for(int g=0;g<4;g++)
      #pragma unroll
      for(int b=0;b<4;b++)
        acc[g*4+b]=hdot2(wu[g],xu[b],acc[g*4+b]);
  }
}

// ---------------- prep kernels ----------------

__global__ __launch_bounds__(256) void k_postab(float* __restrict__ pt){
  int idx=blockIdx.x*256+threadIdx.x; if(idx>=SQ*200) return;
  int t=idx/200, j=idx%200;
  double ang=(double)(t+1)*pow(10000.0, -(double)(2*(j/2))/200.0);
  pt[idx]=(float)((j&1)? cos(ang) : sin(ang));
}

// W_e[k][j] = sum_m tgt_W[k][m] * Wih1[m][j]   (72 x 4096)
__global__ __launch_bounds__(256) void k_we(const float* __restrict__ tgtW, const float* __restrict__ Wih1, float* __restrict__ We){
  int idx=blockIdx.x*256+threadIdx.x;
  int k=idx>>12, j=idx&4095;
  float acc=0.f;
  for(int m=0;m<200;m++) acc+=tgtW[k*200+m]*Wih1[(size_t)m*4096+j];
  We[idx]=acc;
}

// bias[3][4096]
__global__ __launch_bounds__(256) void k_bias(const float* __restrict__ tgtb, const float* __restrict__ Wih1,
    const float* __restrict__ bih1,const float* __restrict__ bhh1,const float* __restrict__ bih2,const float* __restrict__ bhh2,
    const float* __restrict__ bih3,const float* __restrict__ bhh3,float* __restrict__ bias){
  int idx=blockIdx.x*256+threadIdx.x; if(idx>=3*4096) return;
  int l=idx>>12, j=idx&4095;
  float v;
  if(l==0){ v=bih1[j]+bhh1[j]; for(int m=0;m<200;m++) v+=tgtb[m]*Wih1[(size_t)m*4096+j]; }
  else if(l==1) v=bih2[j]+bhh2[j];
  else v=bih3[j]+bhh3[j];
  bias[idx]=v;
}

// packed f16 weights, unit-major [cell][u][k2][4gates], zero-padded k2 strides:
// cell0: 576 k2 (K=1096), stride 2304 u32 ; cell1: 1080 k2 (K=2048), stride 4320 ;
// cell2: 1088 k2 (K=2048), stride 4352.  total u32 = 11239424
__global__ __launch_bounds__(256) void k_packf(const float* __restrict__ We, const float* __restrict__ Whh1,
  const float* __restrict__ Wih2, const float* __restrict__ Whh2,
  const float* __restrict__ Wih3, const float* __restrict__ Whh3, unsigned* __restrict__ P){
  size_t idx=(size_t)blockIdx.x*256+threadIdx.x; // exactly 11,239,424
  const float *A, *Bm; size_t l; int stride, KA, K;
  if(idx < 2359296u){ l=idx; stride=2304; A=We; Bm=Whh1; KA=72; K=1096; }
  else if(idx < 6782976u){ l=idx-2359296u; stride=4320; A=Wih2; Bm=Whh2; KA=1024; K=2048; }
  else { l=idx-6782976u; stride=4352; A=Wih3; Bm=Whh3; KA=1024; K=2048; }
  int u=(int)(l/(size_t)stride); int r=(int)(l-(size_t)u*stride);
  int k2=r>>2, g=r&3, k=2*k2;
  float w0=0.f,w1=0.f;
  if(k<K){
    int col=g*1024+u;
    w0 = (k   < KA)? A[(size_t)k*4096+col]      : Bm[(size_t)(k-KA)*4096+col];
    w1 = (k+1 < KA)? A[(size_t)(k+1)*4096+col]  : Bm[(size_t)(k+1-KA)*4096+col];
  }
  P[idx]=pack16(w0,w1);
}

// outWT[j][u] = out_W[u][j] for u<1024 (h2 part), [72][1024]
__global__ __launch_bounds__(256) void k_outwt(const float* __restrict__ outW, float* __restrict__ outWT){
  int idx=blockIdx.x*256+threadIdx.x; if(idx>=72*1024) return;
  int j=idx>>10, u=idx&1023;
  outWT[idx]=outW[(size_t)u*72+j];
}

// ---------------- encoder ----------------

__global__ __launch_bounds__(256) void k_embed(const float* __restrict__ src, const float* __restrict__ W,
    const float* __restrict__ bias, const float* __restrict__ posb, float* __restrict__ xout){
  __shared__ float s[8][438];
  int row0=blockIdx.x*8, tid=threadIdx.x;
  for(int idx=tid; idx<8*438; idx+=256){ int r=idx/438,k=idx%438; s[r][k]=src[(size_t)(row0+r)*438+k]; }
  __syncthreads();
  int j=tid; if(j<200){
    float acc[8];
    #pragma unroll
    for(int r=0;r<8;r++){ int t=(row0+r)%SQ; acc[r]=bias[j]+posb[t*200+j]; }
    for(int k=0;k<438;k++){
      float w=W[(size_t)k*200+j];
      #pragma unroll
      for(int r=0;r<8;r++) acc[r]+=s[r][k]*w;
    }
    for(int r=0;r<8;r++) xout[(size_t)(row0+r)*200+j]=acc[r];
  }
}

template<int K,int N,int CPT,bool RELU>
__global__ __launch_bounds__(256) void k_gemm8(const float* __restrict__ A, const float* __restrict__ W,
    const float* __restrict__ bias, float* __restrict__ out){
  __shared__ float s[8][K];
  int row0=blockIdx.x*8, tid=threadIdx.x;
  for(int idx=tid; idx<8*K; idx+=256){ int r=idx/K,k=idx%K; s[r][k]=A[(size_t)(row0+r)*K+k]; }
  __syncthreads();
  int j0=tid*CPT;
  float acc[8][CPT];
  #pragma unroll
  for(int r=0;r<8;r++)
    #pragma unroll
    for(int c=0;c<CPT;c++) acc[r][c]=bias[j0+c];
  for(int k=0;k<K;k++){
    float w[CPT];
    #pragma unroll
    for(int c=0;c<CPT;c++) w[c]=W[(size_t)k*N+j0+c];
    #pragma unroll
    for(int r=0;r<8;r++){ float a=s[r][k];
      #pragma unroll
      for(int c=0;c<CPT;c++) acc[r][c]+=a*w[c];
    }
  }
  #pragma unroll
  for(int r=0;r<8;r++)
    #pragma unroll
    for(int c=0;c<CPT;c++){ float v=acc[r][c]; if(RELU) v=fmaxf(v,0.f); out[(size_t)(row0+r)*N+j0+c]=v; }
}

__global__ __launch_bounds__(256) void k_attn(const float* __restrict__ Q, const float* __restrict__ Km,
    const float* __restrict__ V, float* __restrict__ O){
  int bid=blockIdx.x;
  int it=bid%225; int h=(bid/225)&7; int b=bid/1800;
  int i0=it*8;
  int j0=i0-100; if(j0<0) j0=0;
  int j1=i0+7+101; if(j1>SQ) j1=SQ;
  int JN=j1-j0;
  __shared__ unsigned short kld[208][66];
  __shared__ unsigned short vld[208][66];
  __shared__ float q[8][64];
  __shared__ float sc[8][208];
  int tid=threadIdx.x;
  for(int idx=tid; idx<JN*64; idx+=256){
    int j=idx>>6, d=idx&63;
    size_t src=((size_t)(b*SQ+j0+j)*8+h)*64+d;
    kld[j][d]=f2bf(Km[src]);
    vld[j][d]=f2bf(V[src]);
  }
  for(int idx=tid; idx<8*64; idx+=256){ int r=idx>>6,d=idx&63; q[r][d]=Q[((size_t)(b*SQ+i0+r)*8+h)*64+d]; }
  __syncthreads();
  {
    int r=tid>>5, js=tid&31;
    int i=i0+r;
    for(int j=js;j<JN;j+=32){
      int jg=j0+j; int diff=i-jg; if(diff<0) diff=-diff;
      float s=-1e30f;
      if(diff<=100){
        s=0.f;
        for(int d=0;d<64;d++) s+=q[r][d]*bf2f(kld[j][d]);
        s*=0.125f;
      }
      sc[r][j]=s;
    }
  }
  __syncthreads();
  {
    int wv=tid>>6, lane=tid&63;
    for(int rr=wv*2; rr<wv*2+2; rr++){
      float m=-1e30f;
      for(int j=lane;j<JN;j+=64) m=fmaxf(m,sc[rr][j]);
      for(int o=32;o;o>>=1) m=fmaxf(m,__shfl_xor(m,o));
      float sum=0.f;
      for(int j=lane;j<JN;j+=64){ float e=__expf(sc[rr][j]-m); sc[rr][j]=e; sum+=e; }
      for(int o=32;o;o>>=1) sum+=__shfl_xor(sum,o);
      float inv=1.f/sum;
      for(int j=lane;j<JN;j+=64) sc[rr][j]*=inv;
    }
  }
  __syncthreads();
  {
    int d=tid&63, rb=tid>>6;
    for(int rr=rb; rr<8; rr+=4){
      float acc=0.f;
      for(int j=0;j<JN;j++) acc+=sc[rr][j]*bf2f(vld[j][d]);
      O[((size_t)(b*SQ+i0+rr)*8+h)*64+d]=acc;
    }
  }
}

template<int K>
__global__ __launch_bounds__(256) void k_matln(const float* __restrict__ A, const float* __restrict__ W,
    const float* __restrict__ bias, const float* __restrict__ g, const float* __restrict__ bt, float* __restrict__ x){
  __shared__ float s[8][K];
  __shared__ float y[8][200];
  int row0=blockIdx.x*8, tid=threadIdx.x;
  for(int idx=tid; idx<8*K; idx+=256){ int r=idx/K,k=idx%K; s[r][k]=A[(size_t)(row0+r)*K+k]; }
  __syncthreads();
  if(tid<200){
    int j=tid;
    float acc[8];
    #pragma unroll
    for(int r=0;r<8;r++) acc[r]=bias[j];
    for(int k=0;k<K;k++){
      float w=W[(size_t)k*200+j];
      #pragma unroll
      for(int r=0;r<8;r++) acc[r]+=s[r][k]*w;
    }
    #pragma unroll
    for(int r=0;r<8;r++) y[r][j]=acc[r]+x[(size_t)(row0+r)*200+j];
  }
  __syncthreads();
  int wv=tid>>6, lane=tid&63;
  for(int rr=wv*2; rr<wv*2+2; rr++){
    float sm=0.f,s2=0.f;
    for(int j=lane;j<200;j+=64){ float v=y[rr][j]; sm+=v; s2+=v*v; }
    for(int o=32;o;o>>=1){ sm+=__shfl_xor(sm,o); s2+=__shfl_xor(s2,o); }
    float mean=sm*(1.f/200.f);
    float var=s2*(1.f/200.f)-mean*mean;
    float inv=rsqrtf(var+1e-5f);
    for(int j=lane;j<200;j+=64) x[(size_t)(row0+rr)*200+j]=(y[rr][j]-mean)*inv*g[j]+bt[j];
  }
}

__global__ __launch_bounds__(320) void k_encpart(const float* __restrict__ x, const float* __restrict__ outW,
    const float* __restrict__ outb, float* __restrict__ ep){
  int t=blockIdx.x, tid=threadIdx.x;
  __shared__ float el[4][200];
  for(int idx=tid; idx<800; idx+=320){ int b=idx/200,k=idx%200; el[b][k]=x[((size_t)b*SQ+t)*200+k]; }
  __syncthreads();
  if(tid<288){
    int b=tid/72, j=tid%72;
    float acc=outb[j];
    for(int k=0;k<200;k++) acc+=el[b][k]*outW[(size_t)(1024+k)*72+j];
    ep[((size_t)b*SQ+t)*72+j]=acc;
  }
}

// ---------------- persistent decoder: 2-group layer pipeline ----------------
// Group A = blocks 0..127: cell0 (8 units) + cell1 (8 units) per block.
// Group B = blocks 128..255: cell2 (8 units) + fb projection.
// Per-group 128-block tree barrier (8 groups x 16). h ring depth 4.
// All compute paths have COMPILE-TIME NIT/NKS so w[] stays in VGPRs (round-4
// regression was a scratch spill from runtime bounds: VGPR 128->80, FETCH 39GB).
// red[] oversized (dynamically indexed => not eliminable) to force 1 block/CU.

__global__ __launch_bounds__(512,2) void k_dec(
  const uint4* __restrict__ P4, const float* __restrict__ bias,
  unsigned* __restrict__ hbufU, unsigned* __restrict__ fbbufU,
  unsigned* __restrict__ h2allU, unsigned* __restrict__ bar,
  const float* __restrict__ tgt, const float* __restrict__ bos,
  const float* __restrict__ h_init, const float* __restrict__ c_init,
  const float* __restrict__ encp, const float* __restrict__ outWT)
{
  __shared__ __align__(16) unsigned xs2[1116*4]; // 17856B: A:[dec36|h0 512|h1 512|pad], B:[h1 512|h2 512|pad]
  __shared__ float red[16*513+7600];             // 63232B: 32832 used + pad -> total LDS ~82.5KB => 1 block/CU
  __shared__ float gsum[256];
  __shared__ float c_lds[64];
  __shared__ float htmp[64];
  int tid=threadIdx.x, blk=blockIdx.x;
  bool isA = blk<128;
  int lblk = isA? blk : blk-128;

  // thread -> (slot, ks); wave-uniform boundaries (A: waves0-2=cell0, 3-7=cell1)
  int slot,ks,cell;
  if(isA){
    if(tid<192){ slot=tid/24; ks=tid-slot*24; cell=0; }
    else { int l=tid-192; slot=8+l/40; ks=l-(slot-8)*40; cell=1; }
  } else { slot=tid>>6; ks=tid&63; cell=2; }
  int unit = lblk*8 + (slot&7);
  size_t ubase4 = (cell==0)? (size_t)unit*576 :
                  (cell==1)? (589824u + (size_t)unit*1080) :
                             (1695744u + (size_t)unit*1088);

  // t-invariant weight preload into VGPRs (literal bounds per path)
  uint4 w[27];
  if(isA){
    if(tid<192){
      #pragma unroll
      for(int i=0;i<24;i++) w[i]=P4[ubase4 + (size_t)ks + (size_t)i*24];
    } else {
      #pragma unroll
      for(int i=0;i<27;i++) w[i]=P4[ubase4 + (size_t)ks + (size_t)i*40];
    }
  } else {
    #pragma unroll
    for(int i=0;i<17;i++) w[i]=P4[ubase4 + (size_t)ks + (size_t)i*64];
  }

  // per-thread stage descriptors (t-invariant); dty: 0=h row, 1=dec_in, 2=pad, 3=none
  int dty[3], dlp[3];
  #pragma unroll
  for(int q=0;q<3;q++){
    int r=tid+512*q; dty[q]=3; dlp[q]=0;
    if(isA){
      if(r<36){ dty[q]=1; dlp[q]=2*r; }
      else if(r<548){ dty[q]=0; dlp[q]=(r-36)*2; }          // h0: layer0
      else if(r<1060){ dty[q]=0; dlp[q]=(512+(r-548))*2; }  // h1: layer1
      else if(r<1116){ dty[q]=2; }
    } else {
      if(r<512){ dty[q]=0; dlp[q]=(512+r)*2; }              // h1: layer1
      else if(r<1024){ dty[q]=0; dlp[q]=(1024+(r-512))*2; } // h2: layer2
      else if(r<1088){ dty[q]=2; }
    }
  }

  // c state init (LDS-resident for all 1800 steps)
  if(isA){ if(tid<64){ int s=tid>>2,b=tid&3; int cl=(s<8)?0:1;
           c_lds[tid]=c_init[((size_t)cl*4+b)*1024 + lblk*8+(s&7)]; } }
  else   { if(tid<32){ int s=tid>>2,b=tid&3;
           c_lds[tid]=c_init[((size_t)2*4+b)*1024 + lblk*8+s]; } }
  __syncthreads();

  const unsigned long long* hb64=(const unsigned long long*)hbufU;
  unsigned gen=0;
  for(int t=0;t<SQ;t++){
    bool fb=(t>0)&&(t%11==0);

    // ---- B: fb projection (h2(t-1) is B-internal & barrier'd) ----
    if(!isA && fb){
      if(lblk<72 && tid<256){
        int j=lblk, b=tid>>6, lane=tid&63, sl=(t-1)&3;
        float s=0.f;
        #pragma unroll
        for(int q=0;q<8;q++){
          int u2=lane+q*64;
          unsigned v=aload(&hbufU[(size_t)((sl*3+2)*512+u2)*4+b]);
          s += lo16(v)*outWT[(size_t)j*1024+2*u2] + hi16(v)*outWT[(size_t)j*1024+2*u2+1];
        }
        #pragma unroll
        for(int o=32;o;o>>=1) s+=__shfl_xor(s,o);
        if(lane==0) astore(&fbbufU[b*72+j], __float_as_uint(s + encp[((size_t)b*SQ+(t-1))*72+j]));
      }
      __syncthreads();  // drains vmcnt -> fbbuf stores acked before counter bump
      if(tid==0 && lblk<72) __hip_atomic_fetch_add(&bar[640],1u,__ATOMIC_RELAXED,AGT);
    }

    // ---- dependency polls ----
    if(isA){
      if(tid<64){
        if(t>=2){ while((int)aload(&bar[608]) < t-2) __builtin_amdgcn_s_sleep(1); }  // ring throttle
        if(fb){ unsigned tc=72u*(unsigned)(t/11);
                while(aload(&bar[640]) < tc) __builtin_amdgcn_s_sleep(1); }          // fb ready
      }
    } else if(t>0){
      if(tid<64){ while((int)aload(&bar[576]) < t) __builtin_amdgcn_s_sleep(1); }    // h1(t-1) ready
      __syncthreads();
    }

    // ---- stage x (f16 pairs) ----
    if(t==0){
      #pragma unroll
      for(int q=0;q<3;q++){
        int ty=dty[q]; if(ty==3) continue;
        uint4 vv={0u,0u,0u,0u};
        if(ty==1){
          int j=dlp[q];
          const float2 f0=*(const float2*)&bos[0*72+j];
          const float2 f1=*(const float2*)&bos[1*72+j];
          const float2 f2=*(const float2*)&bos[2*72+j];
          const float2 f3=*(const float2*)&bos[3*72+j];
          vv.x=pack16(f0.x,f0.y); vv.y=pack16(f1.x,f1.y);
          vv.z=pack16(f2.x,f2.y); vv.w=pack16(f3.x,f3.y);
        } else if(ty==0){
          int lp=dlp[q]>>10, pr=(dlp[q]&1023)>>1;
          const float2 f0=*(const float2*)&h_init[((size_t)lp*4+0)*1024+2*pr];
          const float2 f1=*(const float2*)&h_init[((size_t)lp*4+1)*1024+2*pr];
          const float2 f2=*(const float2*)&h_init[((size_t)lp*4+2)*1024+2*pr];
          const float2 f3=*(const float2*)&h_init[((size_t)lp*4+3)*1024+2*pr];
          vv.x=pack16(f0.x,f0.y); vv.y=pack16(f1.x,f1.y);
          vv.z=pack16(f2.x,f2.y); vv.w=pack16(f3.x,f3.y);
        }
        *(uint4*)&xs2[(size_t)(tid+512*q)*4]=vv;
      }
    } else {
      size_t pvoff=(size_t)(((t-1)&3)*3*512*2);
      #pragma unroll
      for(int q=0;q<3;q++){
        int ty=dty[q]; if(ty>=2) continue;
        uint4 vv;
        if(ty==0){
          unsigned long long a=aload64(hb64+pvoff+dlp[q]);
          unsigned long long c=aload64(hb64+pvoff+dlp[q]+1);
          vv.x=(unsigned)a; vv.y=(unsigned)(a>>32);
          vv.z=(unsigned)c; vv.w=(unsigned)(c>>32);
        } else {
          int j=dlp[q];
          if(fb){
            vv.x=pack16(__uint_as_float(aload(&fbbufU[0*72+j])),__uint_as_float(aload(&fbbufU[0*72+j+1])));
            vv.y=pack16(__uint_as_float(aload(&fbbufU[1*72+j])),__uint_as_float(aload(&fbbufU[1*72+j+1])));
            vv.z=pack16(__uint_as_float(aload(&fbbufU[2*72+j])),__uint_as_float(aload(&fbbufU[2*72+j+1])));
            vv.w=pack16(__uint_as_float(aload(&fbbufU[3*72+j])),__uint_as_float(aload(&fbbufU[3*72+j+1])));
          } else {
            const float2 f0=*(const float2*)&tgt[((size_t)0*SQ+t)*72+j];
            const float2 f1=*(const float2*)&tgt[((size_t)1*SQ+t)*72+j];
            const float2 f2=*(const float2*)&tgt[((size_t)2*SQ+t)*72+j];
            const float2 f3=*(const float2*)&tgt[((size_t)3*SQ+t)*72+j];
            vv.x=pack16(f0.x,f0.y); vv.y=pack16(f1.x,f1.y);
            vv.z=pack16(f2.x,f2.y); vv.w=pack16(f3.x,f3.y);
          }
        }
        *(uint4*)&xs2[(size_t)(tid+512*q)*4]=vv;
      }
    }
    __syncthreads();

    // ---- gates (compile-time paths) ----
    {
      float acc[16];
      #pragma unroll
      for(int a=0;a<16;a++) acc[a]=0.f;
      if(isA){
        if(tid<192) gate_acc<24,24>(w,xs2,ks,0,acc);
        else        gate_acc<27,40>(w,xs2,ks,36,acc);
      } else        gate_acc<17,64>(w,xs2,ks,0,acc);
      #pragma unroll
      for(int a=0;a<16;a++) red[a*513+tid]=acc[a];
    }
    __syncthreads();

    // ---- per-unit reduce + bias ----
    if(isA){
      if(tid<256){
        int s=tid>>4, a=tid&15;
        int base = (s<8)? s*24 : 192+(s-8)*40;
        int n = (s<8)? 24 : 40;
        float sum=0.f;
        for(int j2=0;j2<n;j2++) sum+=red[a*513+base+j2];
        int cl=(s<8)?0:1;
        gsum[tid]=sum+bias[(size_t)cl*4096+(size_t)(a>>2)*1024 + lblk*8+(s&7)];
      }
    } else {
      if(tid<128){
        int s=tid>>4, a=tid&15;
        float sum=0.f;
        for(int j2=0;j2<64;j2++) sum+=red[a*513+s*64+j2];
        gsum[tid]=sum+bias[(size_t)2*4096+(size_t)(a>>2)*1024 + lblk*8+s];
      }
    }
    __syncthreads();

    // ---- pointwise LSTM + h stores (wave 0 only; wave-internal LDS ordering) ----
    if(isA){
      if(tid<64){
        int s=tid>>2,b=tid&3;
        float gi=gsum[s*16+b],gf=gsum[s*16+4+b],gg=gsum[s*16+8+b],go=gsum[s*16+12+b];
        float cp=c_lds[tid];
        float cn=sigm(gf)*cp+sigm(gi)*tanhf(gg);
        float hn=sigm(go)*tanhf(cn);
        c_lds[tid]=cn; htmp[tid]=hn;
        if(!(tid&4)){
          unsigned v=pack16(htmp[tid],htmp[tid+4]);
          int layer=s>>3, sl=s&7;
          int pr=lblk*4+(sl>>1);
          astore(&hbufU[(size_t)(((t&3)*3+layer)*512+pr)*4+b], v);
        }
      }
    } else {
      if(tid<32){
        int s=tid>>2,b=tid&3;
        float gi=gsum[s*16+b],gf=gsum[s*16+4+b],gg=gsum[s*16+8+b],go=gsum[s*16+12+b];
        float cp=c_lds[tid];
        float cn=sigm(gf)*cp+sigm(gi)*tanhf(gg);
        float hn=sigm(go)*tanhf(cn);
        c_lds[tid]=cn; htmp[tid]=hn;
        if(!(tid&4)){
          unsigned v=pack16(htmp[tid],htmp[tid+4]);
          int pr=lblk*4+(s>>1);
          astore(&hbufU[(size_t)(((t&3)*3+2)*512+pr)*4+b], v);
          astore(&h2allU[((size_t)t*4+b)*512+pr], v);
        }
      }
    }

    // ---- per-group tree barrier (8 groups x 16 blocks each side) ----
    __syncthreads();
    if(tid==0){
      int g=blk>>4;  // A: 0..7, B: 8..15
      unsigned r=__hip_atomic_fetch_add(&bar[g*32],1u,__ATOMIC_RELAXED,AGT);
      if(r==gen*16u+15u){
        unsigned rt=__hip_atomic_fetch_add(&bar[isA?512:544],1u,__ATOMIC_RELAXED,AGT);
        if(rt==gen*8u+7u) __hip_atomic_store(&bar[isA?576:608],gen+1u,__ATOMIC_RELAXED,AGT);
      }
      unsigned f;
      do{ __builtin_amdgcn_s_sleep(1);
          f=aload(&bar[isA?576:608]);
      }while(f<gen+1u);
    }
    __syncthreads();
    gen++;
  }
}

// final: out[b][t][j] = h2(t) @ out_W[:1024] + enc_part[b][t][j]
__global__ __launch_bounds__(320) void k_out(const unsigned* __restrict__ h2allU, const float* __restrict__ outW,
    const float* __restrict__ enc_part, float* __restrict__ out){
  int t=blockIdx.x, tid=threadIdx.x;
  __shared__ float h2l[4][1024];
  for(int idx=tid; idx<2048; idx+=320){
    int b=idx>>9, p=idx&511;
    unsigned v=h2allU[((size_t)t*4+b)*512+p];
    h2l[b][2*p]=lo16(v); h2l[b][2*p+1]=hi16(v);
  }
  __syncthreads();
  if(tid<288){
    int b=tid/72, j=tid%72;
    float acc=enc_part[((size_t)b*SQ+t)*72+j];
    for(int u=0;u<1024;u++) acc+=h2l[b][u]*outW[(size_t)u*72+j];
    out[((size_t)b*SQ+t)*72+j]=acc;
  }
}

// ---------------- host ----------------
extern "C" void kernel_launch(void* const* d_in, const int* in_sizes, int n_in,
                              void* d_out, int out_size, void* d_ws, size_t ws_size,
                              hipStream_t stream) {
  (void)in_sizes; (void)n_in; (void)out_size; (void)ws_size;
  const float* src   =(const float*)d_in[0];
  const float* tgt   =(const float*)d_in[1];
  const float* bos   =(const float*)d_in[2];
  const float* h_init=(const float*)d_in[3];
  const float* c_init=(const float*)d_in[4];
  const float* eW    =(const float*)d_in[6];
  const float* eb    =(const float*)d_in[7];
  const float* Wq    =(const float*)d_in[8];
  const float* bq    =(const float*)d_in[9];
  const float* Wk    =(const float*)d_in[10];
  const float* bk    =(const float*)d_in[11];
  const float* Wv    =(const float*)d_in[12];
  const float* bv    =(const float*)d_in[13];
  const float* Wo    =(const float*)d_in[14];
  const float* bo    =(const float*)d_in[15];
  const float* ln1g  =(const float*)d_in[16];
  const float* ln1b  =(const float*)d_in[17];
  const float* W1    =(const float*)d_in[18];
  const float* b1    =(const float*)d_in[19];
  const float* W2    =(const float*)d_in[20];
  const float* b2    =(const float*)d_in[21];
  const float* ln2g  =(const float*)d_in[22];
  const float* ln2b  =(const float*)d_in[23];
  const float* tgtW  =(const float*)d_in[24];
  const float* tgtb  =(const float*)d_in[25];
  const float* Wih1  =(const float*)d_in[26];
  const float* Whh1  =(const float*)d_in[27];
  const float* bih1  =(const float*)d_in[28];
  const float* bhh1  =(const float*)d_in[29];
  const float* Wih2  =(const float*)d_in[30];
  const float* Whh2  =(const float*)d_in[31];
  const float* bih2  =(const float*)d_in[32];
  const float* bhh2  =(const float*)d_in[33];
  const float* Wih3  =(const float*)d_in[34];
  const float* Whh3  =(const float*)d_in[35];
  const float* bih3  =(const float*)d_in[36];
  const float* bhh3  =(const float*)d_in[37];
  const float* outW  =(const float*)d_in[38];
  const float* outb  =(const float*)d_in[39];
  float* out=(float*)d_out;

  char* wsb=(char*)d_ws; size_t off=0;
  auto alloc=[&](size_t bytes)->void*{ void* p=wsb+off; off+=(bytes+255)&~(size_t)255; return p; };
  unsigned* Pf   =(unsigned*)alloc((size_t)11239424*4);   // 44.96 MB packed f16 weights
  float* We   =(float*)alloc((size_t)72*4096*4);
  float* bias =(float*)alloc((size_t)3*4096*4);
  float* outWT=(float*)alloc((size_t)72*1024*4);
  unsigned* hbufU =(unsigned*)alloc((size_t)4*3*512*4*4); // depth-4 ring
  unsigned* fbbufU=(unsigned*)alloc((size_t)4*72*4);
  unsigned* bar   =(unsigned*)alloc(4096);
  float* encp =(float*)alloc((size_t)7200*72*4);
  float* posb =(float*)alloc((size_t)SQ*200*4);
  float* xb   =(float*)alloc((size_t)7200*200*4);
  float* qb   =(float*)alloc((size_t)7200*512*4);
  float* kb   =(float*)alloc((size_t)7200*512*4);
  float* vb   =(float*)alloc((size_t)7200*512*4);
  float* ob   =(float*)alloc((size_t)7200*512*4);
  unsigned* h2allU=(unsigned*)qb; // alias: dead after encoder; 14.74MB fits
  float* mid  =vb;                // alias for FFN intermediate
  (void)kb; (void)ob;

  // prep
  k_postab<<<(SQ*200+255)/256,256,0,stream>>>(posb);
  k_we<<<72*4096/256,256,0,stream>>>(tgtW,Wih1,We);
  k_bias<<<48,256,0,stream>>>(tgtb,Wih1,bih1,bhh1,bih2,bhh2,bih3,bhh3,bias);
  k_packf<<<43904,256,0,stream>>>(We,Whh1,Wih2,Whh2,Wih3,Whh3,Pf);
  k_outwt<<<(72*1024+255)/256,256,0,stream>>>(outW,outWT);

  // encoder
  k_embed<<<900,256,0,stream>>>(src,eW,eb,posb,xb);
  for(int l=0;l<2;l++){
    k_gemm8<200,512,2,false><<<900,256,0,stream>>>(xb,Wq+(size_t)l*200*512,bq+l*512,qb);
    k_gemm8<200,512,2,false><<<900,256,0,stream>>>(xb,Wk+(size_t)l*200*512,bk+l*512,kb);
    k_gemm8<200,512,2,false><<<900,256,0,stream>>>(xb,Wv+(size_t)l*200*512,bv+l*512,vb);
    k_attn<<<7200,256,0,stream>>>(qb,kb,vb,ob);
    k_matln<512><<<900,256,0,stream>>>(ob,Wo+(size_t)l*512*200,bo+l*200,ln1g+l*200,ln1b+l*200,xb);
    k_gemm8<200,1024,4,true><<<900,256,0,stream>>>(xb,W1+(size_t)l*200*1024,b1+l*1024,mid);
    k_matln<1024><<<900,256,0,stream>>>(mid,W2+(size_t)l*1024*200,b2+l*200,ln2g+l*200,ln2b+l*200,xb);
  }
  k_encpart<<<SQ,320,0,stream>>>(xb,outW,outb,encp);

  // persistent decoder (single dispatch, 2-group pipelined barriers)
  hipMemsetAsync(bar,0,4096,stream);
  k_dec<<<NBLK,512,0,stream>>>((const uint4*)Pf,bias,hbufU,fbbufU,h2allU,bar,
                               tgt,bos,h_init,c_init,encp,outWT);

  // output projection
  k_out<<<SQ,320,0,stream>>>(h2allU,outW,encp,out);
}